// Round 3
// baseline (19840.117 us; speedup 1.0000x reference)
//
#include <hip/hip_runtime.h>
#include <hip/hip_bf16.h>

// ---------------------------------------------------------------------------
// Decoder (Tacotron-style) on MI355X. Round 4 RESUBMIT (round-2 bench died in
// infra: "container failed twice" at acquire/push layer; kernel never ran).
// Source is byte-identical to round-2 submission except this header.
// - lw / lcgT tables moved LDS -> global (L1-resident, wave-uniform loads:
//   ~1-4cyc/instr vs ds_read_b128 12cyc). R3+R5 were ~40us/step of LDS pipe.
// - R5 retiled: 4 t-groups x 4 a-groups (2 t/lane, 32 a/wave) -> half the
//   broadcast instr count; conv results passed pre-packed f16 via cbuf.
// - procF loads back to temporal (round-3 nt was wrong: 1MB/XCD fits L2).
// - biases cached in LDS (removes L2 latency chains in combine stages).
// - Numerics identical to round 3 (same values, same pack points).
// ---------------------------------------------------------------------------

typedef unsigned int u32;

#ifndef __has_builtin
#define __has_builtin(x) 0
#endif

#define NSTEP 100

// workspace offsets in 4-byte units
#define PK_ATTIH 0                      // 320*768
#define PK_ATTHH 245760                 // 128*768
#define PK_Q     344064                 // 128*128
#define PK_PD    360448                 // 384*256
#define PK_D1IH  458752                 // 128*768
#define PK_D1HH  557056
#define PK_D2IH  655360
#define PK_D2HH  753664
#define PK_MEL   851968                 // 128*560
#define W1T_U    923648                 // 80*256 fp32
#define W2T_U    944128                 // 256*128 fp32
#define PROCF_U  976896                 // half[64*512*128] = 2097152 u32
#define P2ALL_U  3074048                // float[100*64*128]
#define INPT_U   3893248                // temp: 128*512 fp32 (dead after proc_kern)
#define LWP_U    3893248                // u32[2048]  (reuses INPT region)
#define LCGT_U   3895296                // f32[1984]  (reuses INPT region)

#define OUT_ATT  3584000
#define OUT_STOP 6860800

typedef _Float16 h2 __attribute__((ext_vector_type(2)));
typedef float f32x4 __attribute__((ext_vector_type(4)));
union U4 { uint4 v; _Float16 h[8]; };

__device__ __forceinline__ float fastrcp(float x) { return __builtin_amdgcn_rcpf(x); }
__device__ __forceinline__ float sig_p(float x) { return 1.f / (1.f + __expf(-x)); }
__device__ __forceinline__ float tanh_f(float x) {
    x = fminf(fmaxf(x, -15.f), 15.f);
    float e2 = __expf(2.f * x);
    return (e2 - 1.f) * fastrcp(e2 + 1.f);
}

__device__ __forceinline__ float dot2(u32 w, u32 x, float acc) {
    h2 wh = __builtin_bit_cast(h2, w);
    h2 xh = __builtin_bit_cast(h2, x);
#if __has_builtin(__builtin_amdgcn_fdot2)
    return __builtin_amdgcn_fdot2(wh, xh, acc, false);
#else
    return acc + (float)wh.x * (float)xh.x + (float)wh.y * (float)xh.y;
#endif
}

__device__ __forceinline__ u32 packh2(float a, float b) {
    h2 h; h.x = (_Float16)a; h.y = (_Float16)b;
    return __builtin_bit_cast(u32, h);
}

// non-temporal (evict-first) loads for the big one-pass streams
__device__ __forceinline__ float4 ntload_f4(const float* p) {
    f32x4 v = __builtin_nontemporal_load((const f32x4*)p);
    float4 r; r.x = v.x; r.y = v.y; r.z = v.z; r.w = v.w; return r;
}
__device__ __forceinline__ float ntload_f(const float* p) {
    return __builtin_nontemporal_load(p);
}

// transpose: src (O x K) row-major -> dst (K x O)  (prenet weights, fp32)
__global__ void tkern(const float* __restrict__ src, float* __restrict__ dst, int O, int K) {
    int i = blockIdx.x * blockDim.x + threadIdx.x;
    if (i < O * K) {
        int o = i % O, k = i / O;
        dst[i] = src[o * K + k];
    }
}

// pack fp32 (O x K) -> f16 pairs: dst[(k/2)*O + o] = (w[o][2p], w[o][2p+1])
__global__ void packw(const float* __restrict__ src, u32* __restrict__ dst, int O, int K) {
    int i = blockIdx.x * blockDim.x + threadIdx.x;
    int n = O * (K >> 1);
    if (i < n) {
        int o = i % O, p = i / O;
        dst[i] = packh2(src[o * K + 2 * p], src[o * K + 2 * p + 1]);
    }
}

// loc_w (128 x 32) -> f16 c-pairs, [a][cp] layout
__global__ void packlw(const float* __restrict__ lwg, u32* __restrict__ dst) {
    int i = blockIdx.x * blockDim.x + threadIdx.x;
    if (i < 2048) dst[i] = packh2(lwg[2 * i], lwg[2 * i + 1]);
}

// loc_conv (32 x 2 x 31) -> transposed f32 [ch*31+k][c]
__global__ void tlcg(const float* __restrict__ lcg, float* __restrict__ dst) {
    int i = blockIdx.x * blockDim.x + threadIdx.x;
    if (i < 1984) { int k = i >> 5, c = i & 31; dst[i] = lcg[c * 62 + k]; }
}

__global__ void prenet_kern(const float* __restrict__ memory,
                            const float* __restrict__ w1T, const float* __restrict__ b1,
                            const float* __restrict__ w2T, const float* __restrict__ b2,
                            float* __restrict__ p2all) {
    __shared__ float mi[80];
    __shared__ float p1[256];
    int blk = blockIdx.x;
    int t = blk >> 6, b = blk & 63;
    int tid = threadIdx.x;
    if (tid < 80) mi[tid] = (t == 0) ? 0.f : memory[(b * 700 + (7 * t - 1)) * 80 + tid];
    __syncthreads();
    float acc = b1[tid];
#pragma unroll 4
    for (int k = 0; k < 80; k++) acc += mi[k] * w1T[k * 256 + tid];
    p1[tid] = fmaxf(acc, 0.f);
    __syncthreads();
    if (tid < 128) {
        float a2 = b2[tid];
#pragma unroll 4
        for (int k = 0; k < 256; k++) a2 += p1[k] * w2T[k * 128 + tid];
        p2all[(t * 64 + b) * 128 + tid] = fmaxf(a2, 0.f);
    }
}

// proc_in -> f16, layout [b][t][a]
__global__ void proc_kern(const float* __restrict__ inputs, const float* __restrict__ inpT,
                          _Float16* __restrict__ procF) {
    __shared__ float xin[8][512];
    int blk = blockIdx.x;
    int b = blk >> 6, t0 = (blk & 63) << 3;
    int tid = threadIdx.x;
    for (int i = tid; i < 8 * 512; i += 1024)
        xin[i >> 9][i & 511] = inputs[((size_t)b * 512 + t0 + (i >> 9)) * 512 + (i & 511)];
    __syncthreads();
    int r = tid >> 7, a = tid & 127;
    float acc = 0.f;
#pragma unroll 4
    for (int d = 0; d < 512; d++) acc += xin[r][d] * inpT[d * 128 + a];
    procF[((size_t)(b * 512) + t0 + r) * 128 + a] = (_Float16)acc;
}

__launch_bounds__(1024, 4)
__global__ void decoder_kern(const float* __restrict__ inputs,
                             const u32* __restrict__ wsu,
                             const float* __restrict__ att_b_ih, const float* __restrict__ att_b_hh,
                             const float* __restrict__ v_w, const float* __restrict__ v_b,
                             const float* __restrict__ pd_b,
                             const float* __restrict__ d1b_ih, const float* __restrict__ d1b_hh,
                             const float* __restrict__ d2b_ih, const float* __restrict__ d2b_hh,
                             const float* __restrict__ mel_b,
                             const float* __restrict__ stop_w, const float* __restrict__ stop_b,
                             float* __restrict__ out) {
    const int b = blockIdx.x;
    const int tid = threadIdx.x;

    const uint4* w_attih = (const uint4*)(wsu + PK_ATTIH);
    const uint4* w_atthh = (const uint4*)(wsu + PK_ATTHH);
    const uint4* w_pd    = (const uint4*)(wsu + PK_PD);
    const uint4* w_d1ih  = (const uint4*)(wsu + PK_D1IH);
    const uint4* w_d1hh  = (const uint4*)(wsu + PK_D1HH);
    const uint4* w_d2ih  = (const uint4*)(wsu + PK_D2IH);
    const uint4* w_d2hh  = (const uint4*)(wsu + PK_D2HH);
    const uint4* w_mel   = (const uint4*)(wsu + PK_MEL);
    const _Float16* procF = (const _Float16*)(wsu + PROCF_U);
    const float* p2all   = (const float*)(wsu + P2ALL_U);
    const uint4* lw4     = (const uint4*)(wsu + LWP_U);    // L1-resident broadcast table
    const float* lcgTg   = (const float*)(wsu + LCGT_U);   // L1-resident broadcast table

    __shared__ float h_att[256], h1[256], h2[256], dec[256];
    __shared__ float awp[542], awcp[542];
    __shared__ __align__(16) float pqv[256];   // interleaved [pq[a], v_w[a]]
    __shared__ float ebuf[512], red[32], mout[560];
    __shared__ u32 cbuf[16 * 513];             // conv result, f16 c-pairs, [cp][t]
    __shared__ __align__(16) float scrA[4096];
    __shared__ __align__(16) float scrB[3072];
    __shared__ u32 xpatt[320];   // [p2 pairs 0..63 | ctx pairs 64..319]
    __shared__ u32 xppd[384];    // [h_att pairs 0..127 | ctx pairs 128..383]
    __shared__ u32 decp[128], h1p[128], h2p[128];
    __shared__ float bias[5424]; // 0:att_ih 768:att_hh 1536:d1ih 2304:d1hh 3072:d2ih 3840:d2hh 4608:pd 4864:mel
    __shared__ float stopws[816];

    for (int i = tid; i < 256; i += 1024) { h_att[i] = 0.f; h1[i] = 0.f; h2[i] = 0.f; dec[i] = 0.f; }
    for (int i = tid; i < 542; i += 1024) { awp[i] = 0.f; awcp[i] = 0.f; }
    for (int i = tid; i < 320; i += 1024) xpatt[i] = 0u;
    for (int i = tid; i < 384; i += 1024) xppd[i] = 0u;
    if (tid < 128) { decp[tid] = 0u; h1p[tid] = 0u; h2p[tid] = 0u; }
    if (tid < 768) {
        bias[tid] = att_b_ih[tid]; bias[768 + tid] = att_b_hh[tid];
        bias[1536 + tid] = d1b_ih[tid]; bias[2304 + tid] = d1b_hh[tid];
        bias[3072 + tid] = d2b_ih[tid]; bias[3840 + tid] = d2b_hh[tid];
    }
    if (tid < 256) bias[4608 + tid] = pd_b[tid];
    if (tid < 560) bias[4864 + tid] = mel_b[tid];
    if (tid < 816) stopws[tid] = stop_w[tid];
    if (tid < 128) { pqv[2 * tid] = 0.f; pqv[2 * tid + 1] = v_w[tid]; }
    if (tid >= 960) {   // pack p2 for step 0
        int j = tid - 960;
        xpatt[j] = packh2(p2all[(size_t)b * 128 + 2 * j], p2all[(size_t)b * 128 + 2 * j + 1]);
    }
    const float vb0 = v_b[0];
    const float sb0 = stop_b[0];
    __syncthreads();

    for (int step = 0; step < NSTEP; step++) {
        // ---- R1: att-GRU gate partials (768 thr: 192 og x 4 ks) ----
        if (tid < 768) {
            const int og = tid % 192;
            const int ks = tid / 192;
            float4 ai = {0.f, 0.f, 0.f, 0.f};
            float4 ah4 = {0.f, 0.f, 0.f, 0.f};
#pragma unroll 8
            for (int p = ks * 80; p < ks * 80 + 80; p++) {
                uint4 w = w_attih[p * 192 + og];
                u32 x = xpatt[p];
                ai.x = dot2(w.x, x, ai.x); ai.y = dot2(w.y, x, ai.y);
                ai.z = dot2(w.z, x, ai.z); ai.w = dot2(w.w, x, ai.w);
            }
#pragma unroll 8
            for (int p = ks * 32; p < ks * 32 + 32; p++) {
                uint4 w = w_atthh[p * 192 + og];
                u32 x = xppd[p];
                ah4.x = dot2(w.x, x, ah4.x); ah4.y = dot2(w.y, x, ah4.y);
                ah4.z = dot2(w.z, x, ah4.z); ah4.w = dot2(w.w, x, ah4.w);
            }
            *(float4*)&scrA[ks * 768 + og * 4] = ai;
            *(float4*)&scrB[ks * 768 + og * 4] = ah4;
        }
        __syncthreads();

        // ---- R2: att-GRU combine (128 thr x 2 outputs) + pack h_att pairs ----
        if (tid < 128) {
            float hv[2];
#pragma unroll
            for (int j = 0; j < 2; j++) {
                const int o = tid * 2 + j;
                float gr = bias[o], gz = bias[256 + o], gn = bias[512 + o];
                float hr = bias[768 + o], hz = bias[1024 + o], hn = bias[1280 + o];
#pragma unroll
                for (int s = 0; s < 4; s++) {
                    gr += scrA[s * 768 + o]; gz += scrA[s * 768 + 256 + o]; gn += scrA[s * 768 + 512 + o];
                    hr += scrB[s * 768 + o]; hz += scrB[s * 768 + 256 + o]; hn += scrB[s * 768 + 512 + o];
                }
                float r = sig_p(gr + hr), z = sig_p(gz + hz);
                float n = tanh_f(gn + r * hn);
                hv[j] = (1.f - z) * n + z * h_att[o];
                h_att[o] = hv[j];
            }
            xppd[tid] = packh2(hv[0], hv[1]);
        }
        __syncthreads();

        // ---- R3: q full-dot (128 thr -> pqv) || location conv (512 thr, L1 weights) ----
        if (tid < 128) {
            const u32* wqu = wsu + PK_Q;
            float qa = 0.f;
#pragma unroll 8
            for (int p = 0; p < 128; p++) qa = dot2(wqu[p * 128 + tid], xppd[p], qa);
            pqv[2 * tid] = qa;
        } else if (tid >= 512) {
            const int tp = tid - 512;
            float cr[32];
#pragma unroll
            for (int c = 0; c < 32; c++) cr[c] = 0.f;
#pragma clang loop unroll_count(2)
            for (int k = 0; k < 31; k++) {
                float a1 = awp[tp + k], a2 = awcp[tp + k];
                const float4* l1 = (const float4*)&lcgTg[k * 32];
                const float4* l2 = (const float4*)&lcgTg[(31 + k) * 32];
#pragma unroll
                for (int cc = 0; cc < 8; cc++) {
                    float4 w1 = l1[cc], w2 = l2[cc];
                    cr[4 * cc]     += w1.x * a1 + w2.x * a2;
                    cr[4 * cc + 1] += w1.y * a1 + w2.y * a2;
                    cr[4 * cc + 2] += w1.z * a1 + w2.z * a2;
                    cr[4 * cc + 3] += w1.w * a1 + w2.w * a2;
                }
            }
            // hand conv to R5 pre-packed (same f16 pack R5 did before: numerics identical)
#pragma unroll
            for (int cp = 0; cp < 16; cp++) cbuf[cp * 513 + tp] = packh2(cr[2 * cp], cr[2 * cp + 1]);
        }
        __syncthreads();

        // ---- R5: attention energies. 16 waves = 4 t-groups x 4 a-groups,
        //          2 t per lane, lw from global (L1 broadcast) ----
        {
            const int wv = tid >> 6, lane = tid & 63;
            const int tg = wv & 3, ag = wv >> 2;
            const int a0 = ag << 5;
            const int t0 = (tg << 7) + lane;        // and t0+64
            u32 crA[16], crB[16];
#pragma unroll
            for (int cp = 0; cp < 16; cp++) {
                crA[cp] = cbuf[cp * 513 + t0];
                crB[cp] = cbuf[cp * 513 + t0 + 64];
            }
            const uint4* pfA = (const uint4*)(procF + ((size_t)(b * 512 + t0)) * 128 + a0);
            const uint4* pfB = (const uint4*)(procF + ((size_t)(b * 512 + t0 + 64)) * 128 + a0);
            float acc0 = 0.f, acc1 = 0.f;
#pragma unroll
            for (int l = 0; l < 4; l++) {
                U4 uA; uA.v = pfA[l];
                U4 uB; uB.v = pfB[l];
#pragma unroll
                for (int j = 0; j < 8; j++) {
                    const int a = a0 + l * 8 + j;
                    float2 pv = *(const float2*)&pqv[2 * a];
                    uint4 w0 = lw4[a * 4 + 0], w1 = lw4[a * 4 + 1];
                    uint4 w2 = lw4[a * 4 + 2], w3 = lw4[a * 4 + 3];
                    float s0 = pv.x + (float)uA.h[j];
                    float s1 = pv.x + (float)uB.h[j];
                    s0 = dot2(w0.x, crA[0], s0);  s1 = dot2(w0.x, crB[0], s1);
                    s0 = dot2(w0.y, crA[1], s0);  s1 = dot2(w0.y, crB[1], s1);
                    s0 = dot2(w0.z, crA[2], s0);  s1 = dot2(w0.z, crB[2], s1);
                    s0 = dot2(w0.w, crA[3], s0);  s1 = dot2(w0.w, crB[3], s1);
                    s0 = dot2(w1.x, crA[4], s0);  s1 = dot2(w1.x, crB[4], s1);
                    s0 = dot2(w1.y, crA[5], s0);  s1 = dot2(w1.y, crB[5], s1);
                    s0 = dot2(w1.z, crA[6], s0);  s1 = dot2(w1.z, crB[6], s1);
                    s0 = dot2(w1.w, crA[7], s0);  s1 = dot2(w1.w, crB[7], s1);
                    s0 = dot2(w2.x, crA[8], s0);  s1 = dot2(w2.x, crB[8], s1);
                    s0 = dot2(w2.y, crA[9], s0);  s1 = dot2(w2.y, crB[9], s1);
                    s0 = dot2(w2.z, crA[10], s0); s1 = dot2(w2.z, crB[10], s1);
                    s0 = dot2(w2.w, crA[11], s0); s1 = dot2(w2.w, crB[11], s1);
                    s0 = dot2(w3.x, crA[12], s0); s1 = dot2(w3.x, crB[12], s1);
                    s0 = dot2(w3.y, crA[13], s0); s1 = dot2(w3.y, crB[13], s1);
                    s0 = dot2(w3.z, crA[14], s0); s1 = dot2(w3.z, crB[14], s1);
                    s0 = dot2(w3.w, crA[15], s0); s1 = dot2(w3.w, crB[15], s1);
                    acc0 += pv.y * tanh_f(s0);
                    acc1 += pv.y * tanh_f(s1);
                }
            }
            scrB[ag * 512 + t0] = acc0;
            scrB[ag * 512 + t0 + 64] = acc1;
        }
        __syncthreads();

        // ---- R6: softmax over 512 + aw/awc + atts output (3 barriers) ----
        float e_reg = -1e30f;
        if (tid < 512)
            e_reg = scrB[tid] + scrB[512 + tid] + scrB[1024 + tid] + scrB[1536 + tid] + vb0;
        {
            float v = e_reg;
#pragma unroll
            for (int off = 32; off; off >>= 1) v = fmaxf(v, __shfl_down(v, off, 64));
            if (tid < 512 && (tid & 63) == 0) red[tid >> 6] = v;
        }
        __syncthreads();
        float smax = fmaxf(fmaxf(fmaxf(red[0], red[1]), fmaxf(red[2], red[3])),
                           fmaxf(fmaxf(red[4], red[5]), fmaxf(red[6], red[7])));
        float ex = 0.f;
        if (tid < 512) ex = __expf(e_reg - smax);
        {
            float v = ex;
#pragma unroll
            for (int off = 32; off; off >>= 1) v += __shfl_down(v, off, 64);
            if (tid < 512 && (tid & 63) == 0) red[8 + (tid >> 6)] = v;
        }
        __syncthreads();
        if (tid < 512) {
            float ssum = ((red[8] + red[9]) + (red[10] + red[11])) +
                         ((red[12] + red[13]) + (red[14] + red[15]));
            float al = ex * fastrcp(ssum);
            ebuf[tid] = al;
            awp[15 + tid] = al;
            awcp[15 + tid] += al;
            out[OUT_ATT + ((size_t)b * 100 + step) * 512 + tid] = al;
        }
        __syncthreads();

        // ---- R7: ctx partials (1024 thr: 128 dg x 8 ts), nt inputs stream ----
        {
            const int dg = tid & 127, ts = tid >> 7;
            const float* ib = inputs + ((size_t)b * 512 + ts * 64) * 512;
            float4 acc = {0.f, 0.f, 0.f, 0.f};
#pragma unroll 8
            for (int t = 0; t < 64; t++) {
                float al = ebuf[ts * 64 + t];
                float4 xv = ntload_f4(ib + (size_t)t * 512 + dg * 4);
                acc.x += al * xv.x; acc.y += al * xv.y; acc.z += al * xv.z; acc.w += al * xv.w;
            }
            *(float4*)&scrA[ts * 512 + dg * 4] = acc;
        }
        __syncthreads();

        // ---- R8: ctx reduce + pack pairs ----
        if (tid < 256) {
            float s0 = 0.f, s1 = 0.f;
#pragma unroll
            for (int q = 0; q < 8; q++) { s0 += scrA[q * 512 + 2 * tid]; s1 += scrA[q * 512 + 2 * tid + 1]; }
            u32 pr = packh2(s0, s1);
            xpatt[64 + tid] = pr;
            xppd[128 + tid] = pr;
        }
        __syncthreads();

        // ---- R9: pd partials (1024 thr: 64 og x 16 ks) ----
        {
            const int og = tid & 63, ks = tid >> 6;
            float4 acc = {0.f, 0.f, 0.f, 0.f};
#pragma unroll 8
            for (int p = ks * 24; p < ks * 24 + 24; p++) {
                uint4 w = w_pd[p * 64 + og];
                u32 x = xppd[p];
                acc.x = dot2(w.x, x, acc.x); acc.y = dot2(w.y, x, acc.y);
                acc.z = dot2(w.z, x, acc.z); acc.w = dot2(w.w, x, acc.w);
            }
            *(float4*)&scrA[ks * 256 + og * 4] = acc;
        }
        __syncthreads();

        // ---- R10: dec combine + pack ----
        if (tid < 128) {
            float d0 = bias[4608 + 2 * tid], d1 = bias[4608 + 2 * tid + 1];
#pragma unroll
            for (int q = 0; q < 16; q++) { d0 += scrA[q * 256 + 2 * tid]; d1 += scrA[q * 256 + 2 * tid + 1]; }
            dec[2 * tid] = d0; dec[2 * tid + 1] = d1;
            decp[tid] = packh2(d0, d1);
        }
        __syncthreads();

        // ---- R11: GRU1 partials ----
        if (tid < 768) {
            const int og = tid % 192;
            const int ks = tid / 192;
            float4 ai = {0.f, 0.f, 0.f, 0.f};
            float4 ah4 = {0.f, 0.f, 0.f, 0.f};
#pragma unroll 8
            for (int p = ks * 32; p < ks * 32 + 32; p++) {
                uint4 w1 = w_d1ih[p * 192 + og];
                uint4 w2 = w_d1hh[p * 192 + og];
                u32 xd = decp[p], xh = h1p[p];
                ai.x = dot2(w1.x, xd, ai.x); ai.y = dot2(w1.y, xd, ai.y);
                ai.z = dot2(w1.z, xd, ai.z); ai.w = dot2(w1.w, xd, ai.w);
                ah4.x = dot2(w2.x, xh, ah4.x); ah4.y = dot2(w2.y, xh, ah4.y);
                ah4.z = dot2(w2.z, xh, ah4.z); ah4.w = dot2(w2.w, xh, ah4.w);
            }
            *(float4*)&scrA[ks * 768 + og * 4] = ai;
            *(float4*)&scrB[ks * 768 + og * 4] = ah4;
        }
        __syncthreads();

        // ---- R12: GRU1 combine + residual + pack ----
        if (tid < 128) {
            float hv[2], dv[2];
#pragma unroll
            for (int j = 0; j < 2; j++) {
                const int o = tid * 2 + j;
                float gr = bias[1536 + o], gz = bias[1792 + o], gn = bias[2048 + o];
                float hr = bias[2304 + o], hz = bias[2560 + o], hn = bias[2816 + o];
#pragma unroll
                for (int s = 0; s < 4; s++) {
                    gr += scrA[s * 768 + o]; gz += scrA[s * 768 + 256 + o]; gn += scrA[s * 768 + 512 + o];
                    hr += scrB[s * 768 + o]; hz += scrB[s * 768 + 256 + o]; hn += scrB[s * 768 + 512 + o];
                }
                float r = sig_p(gr + hr), z = sig_p(gz + hz);
                float n = tanh_f(gn + r * hn);
                hv[j] = (1.f - z) * n + z * h1[o];
                h1[o] = hv[j];
                dv[j] = hv[j] + dec[o];
                dec[o] = dv[j];
            }
            h1p[tid] = packh2(hv[0], hv[1]);
            decp[tid] = packh2(dv[0], dv[1]);
        }
        __syncthreads();

        // ---- R13: GRU2 partials ----
        if (tid < 768) {
            const int og = tid % 192;
            const int ks = tid / 192;
            float4 ai = {0.f, 0.f, 0.f, 0.f};
            float4 ah4 = {0.f, 0.f, 0.f, 0.f};
#pragma unroll 8
            for (int p = ks * 32; p < ks * 32 + 32; p++) {
                uint4 w1 = w_d2ih[p * 192 + og];
                uint4 w2 = w_d2hh[p * 192 + og];
                u32 xd = decp[p], xh = h2p[p];
                ai.x = dot2(w1.x, xd, ai.x); ai.y = dot2(w1.y, xd, ai.y);
                ai.z = dot2(w1.z, xd, ai.z); ai.w = dot2(w1.w, xd, ai.w);
                ah4.x = dot2(w2.x, xh, ah4.x); ah4.y = dot2(w2.y, xh, ah4.y);
                ah4.z = dot2(w2.z, xh, ah4.z); ah4.w = dot2(w2.w, xh, ah4.w);
            }
            *(float4*)&scrA[ks * 768 + og * 4] = ai;
            *(float4*)&scrB[ks * 768 + og * 4] = ah4;
        }
        __syncthreads();

        // ---- R14: GRU2 combine + residual + pack ----
        if (tid < 128) {
            float hv[2], dv[2];
#pragma unroll
            for (int j = 0; j < 2; j++) {
                const int o = tid * 2 + j;
                float gr = bias[3072 + o], gz = bias[3328 + o], gn = bias[3584 + o];
                float hr = bias[3840 + o], hz = bias[4096 + o], hn = bias[4352 + o];
#pragma unroll
                for (int s = 0; s < 4; s++) {
                    gr += scrA[s * 768 + o]; gz += scrA[s * 768 + 256 + o]; gn += scrA[s * 768 + 512 + o];
                    hr += scrB[s * 768 + o]; hz += scrB[s * 768 + 256 + o]; hn += scrB[s * 768 + 512 + o];
                }
                float r = sig_p(gr + hr), z = sig_p(gz + hz);
                float n = tanh_f(gn + r * hn);
                hv[j] = (1.f - z) * n + z * h2[o];
                h2[o] = hv[j];
                dv[j] = hv[j] + dec[o];
                dec[o] = dv[j];
            }
            h2p[tid] = packh2(hv[0], hv[1]);
            decp[tid] = packh2(dv[0], dv[1]);
        }
        __syncthreads();

        // ---- R15: mel partials (560 thr: 140 og x 4 ks) ----
        if (tid < 560) {
            const int og = tid % 140;
            const int ks = tid / 140;
            float4 acc = {0.f, 0.f, 0.f, 0.f};
#pragma unroll 8
            for (int p = ks * 32; p < ks * 32 + 32; p++) {
                uint4 w = w_mel[p * 140 + og];
                u32 x = decp[p];
                acc.x = dot2(w.x, x, acc.x); acc.y = dot2(w.y, x, acc.y);
                acc.z = dot2(w.z, x, acc.z); acc.w = dot2(w.w, x, acc.w);
            }
            *(float4*)&scrA[ks * 560 + og * 4] = acc;
        }
        __syncthreads();

        // ---- R16: mel reduce + output write (280 thr x 2 outputs) ----
        if (tid < 280) {
#pragma unroll
            for (int j = 0; j < 2; j++) {
                const int o = 2 * tid + j;
                float m = bias[4864 + o];
#pragma unroll
                for (int s = 0; s < 4; s++) m += scrA[s * 560 + o];
                mout[o] = m;
                int mm = o % 80, jj = o / 80;
                out[((size_t)b * 80 + mm) * 700 + 7 * step + jj] = m;
            }
        }
        __syncthreads();

        // ---- R17: stop token || prefetch+pack next p2 (no tail barrier) ----
        {
            float v = 0.f;
            if (tid < 816) v = ((tid < 256) ? dec[tid] : mout[tid - 256]) * stopws[tid];
            if (tid < 832) {
#pragma unroll
                for (int off = 32; off; off >>= 1) v += __shfl_down(v, off, 64);
                if ((tid & 63) == 0) red[tid >> 6] = v;
            }
            if (tid >= 960 && step + 1 < NSTEP) {
                int j = tid - 960;
                const float* p2n = p2all + ((size_t)(step + 1) * 64 + b) * 128;
                xpatt[j] = packh2(ntload_f(p2n + 2 * j), ntload_f(p2n + 2 * j + 1));
            }
        }
        __syncthreads();
        if (tid == 0) {
            float s = sb0;
            for (int w = 0; w < 13; w++) s += red[w];
            out[OUT_STOP + (size_t)b * 100 + step] = s;
        }
        // tail barrier dropped: next R1 touches only scrA/scrB (fenced above),
        // and red is next written in R6, several barriers after tid0's read.
    }
}

extern "C" void kernel_launch(void* const* d_in, const int* in_sizes, int n_in,
                              void* d_out, int out_size, void* d_ws, size_t ws_size,
                              hipStream_t stream) {
    const float* inputs    = (const float*)d_in[0];
    const float* memory    = (const float*)d_in[1];
    const float* prenet_w1 = (const float*)d_in[3];
    const float* prenet_b1 = (const float*)d_in[4];
    const float* prenet_w2 = (const float*)d_in[5];
    const float* prenet_b2 = (const float*)d_in[6];
    const float* att_w_ih  = (const float*)d_in[7];
    const float* att_w_hh  = (const float*)d_in[8];
    const float* att_b_ih  = (const float*)d_in[9];
    const float* att_b_hh  = (const float*)d_in[10];
    const float* q_w       = (const float*)d_in[11];
    const float* inp_w     = (const float*)d_in[12];
    const float* v_w       = (const float*)d_in[13];
    const float* v_b       = (const float*)d_in[14];
    const float* loc_conv  = (const float*)d_in[15];
    const float* loc_w     = (const float*)d_in[16];
    const float* pd_w      = (const float*)d_in[17];
    const float* pd_b      = (const float*)d_in[18];
    const float* d1_w_ih   = (const float*)d_in[19];
    const float* d1_w_hh   = (const float*)d_in[20];
    const float* d1_b_ih   = (const float*)d_in[21];
    const float* d1_b_hh   = (const float*)d_in[22];
    const float* d2_w_ih   = (const float*)d_in[23];
    const float* d2_w_hh   = (const float*)d_in[24];
    const float* d2_b_ih   = (const float*)d_in[25];
    const float* d2_b_hh   = (const float*)d_in[26];
    const float* mel_w     = (const float*)d_in[27];
    const float* mel_b     = (const float*)d_in[28];
    const float* stop_w    = (const float*)d_in[29];
    const float* stop_b    = (const float*)d_in[30];

    u32* wsu = (u32*)d_ws;
    float* out = (float*)d_out;

    auto P = [&](const float* src, int off, int O, int K) {
        int n = O * (K / 2);
        packw<<<(n + 255) / 256, 256, 0, stream>>>(src, wsu + off, O, K);
    };
    P(att_w_ih, PK_ATTIH, 768, 640);
    P(att_w_hh, PK_ATTHH, 768, 256);
    P(q_w,      PK_Q,     128, 256);
    P(pd_w,     PK_PD,    256, 768);
    P(d1_w_ih,  PK_D1IH,  768, 256);
    P(d1_w_hh,  PK_D1HH,  768, 256);
    P(d2_w_ih,  PK_D2IH,  768, 256);
    P(d2_w_hh,  PK_D2HH,  768, 256);
    P(mel_w,    PK_MEL,   560, 256);

    // prenet weight transposes (fp32)
    tkern<<<(256 * 80 + 255) / 256, 256, 0, stream>>>(prenet_w1, (float*)(wsu + W1T_U), 256, 80);
    tkern<<<(128 * 256 + 255) / 256, 256, 0, stream>>>(prenet_w2, (float*)(wsu + W2T_U), 128, 256);

    prenet_kern<<<6400, 256, 0, stream>>>(memory, (float*)(wsu + W1T_U), prenet_b1,
                                          (float*)(wsu + W2T_U), prenet_b2,
                                          (float*)(wsu + P2ALL_U));

    {
        float* inpT = (float*)(wsu + INPT_U);
        tkern<<<(128 * 512 + 255) / 256, 256, 0, stream>>>(inp_w, inpT, 128, 512);
        proc_kern<<<4096, 1024, 0, stream>>>(inputs, inpT, (_Float16*)(wsu + PROCF_U));
    }

    // pack broadcast tables into the (now dead) inpT region — stream-ordered
    // after proc_kern, so no clobber.
    packlw<<<8, 256, 0, stream>>>(loc_w, wsu + LWP_U);
    tlcg<<<8, 256, 0, stream>>>(loc_conv, (float*)(wsu + LCGT_U));

    decoder_kern<<<64, 1024, 0, stream>>>(inputs, wsu,
                                          att_b_ih, att_b_hh, v_w, v_b,
                                          pd_b,
                                          d1_b_ih, d1_b_hh, d2_b_ih, d2_b_hh,
                                          mel_b, stop_w, stop_b, out);
}

// Round 4
// 15094.481 us; speedup vs baseline: 1.3144x; 1.3144x over previous
//
#include <hip/hip_runtime.h>
#include <hip/hip_bf16.h>

// ---------------------------------------------------------------------------
// Decoder (Tacotron-style) on MI355X. Round 5.
// Post-mortem of r3 regression: procF temporal evicted weights from L2
// (FETCH 5.9->12.4GB). Revert to r1 cache config (procF nt, tables in LDS);
// keep cache-neutral VALU wins (R5 retile, cbuf prepack, LDS biases).
// New fetch-reducers (the dominant cost is R7's inputs re-read, 64MB/step):
//  - inputs packed to f16 once -> R7 stream halves (32MB/step)
//  - mel outputs staged contiguously in ws, re-laid-out by a tiny kernel
//    (kills partial-line RMW churn on out)
// Both guarded by ws_size (fallback = round-1 behavior).
// ---------------------------------------------------------------------------

typedef unsigned int u32;

#ifndef __has_builtin
#define __has_builtin(x) 0
#endif

#define NSTEP 100

// workspace offsets in 4-byte units
#define PK_ATTIH 0                      // 320*768
#define PK_ATTHH 245760                 // 128*768
#define PK_Q     344064                 // 128*128
#define PK_PD    360448                 // 384*256
#define PK_D1IH  458752                 // 128*768
#define PK_D1HH  557056
#define PK_D2IH  655360
#define PK_D2HH  753664
#define PK_MEL   851968                 // 128*560
#define W1T_U    923648                 // 80*256 fp32
#define W2T_U    944128                 // 256*128 fp32
#define PROCF_U  976896                 // half[64*512*128] = 2097152 u32
#define P2ALL_U  3074048                // float[100*64*128] = 819200
#define INPT_U   3893248                // temp 128*512 fp32 (dead after proc_kern)
#define MSTG_U   3958784                // float[64*100*560] = 3584000
#define INF16_U  7542784                // half[64*512*512] = 8388608 u32
#define WS_NEED_U 15931392              // total u32 needed for big path

#define OUT_ATT  3584000
#define OUT_STOP 6860800

typedef _Float16 h2 __attribute__((ext_vector_type(2)));
typedef float f32x4 __attribute__((ext_vector_type(4)));
typedef unsigned int u32x4 __attribute__((ext_vector_type(4)));
union U4 { uint4 v; _Float16 h[8]; };

__device__ __forceinline__ float fastrcp(float x) { return __builtin_amdgcn_rcpf(x); }
__device__ __forceinline__ float sig_p(float x) { return 1.f / (1.f + __expf(-x)); }
__device__ __forceinline__ float tanh_f(float x) {
    x = fminf(fmaxf(x, -15.f), 15.f);
    float e2 = __expf(2.f * x);
    return (e2 - 1.f) * fastrcp(e2 + 1.f);
}

__device__ __forceinline__ float dot2(u32 w, u32 x, float acc) {
    h2 wh = __builtin_bit_cast(h2, w);
    h2 xh = __builtin_bit_cast(h2, x);
#if __has_builtin(__builtin_amdgcn_fdot2)
    return __builtin_amdgcn_fdot2(wh, xh, acc, false);
#else
    return acc + (float)wh.x * (float)xh.x + (float)wh.y * (float)xh.y;
#endif
}

__device__ __forceinline__ u32 packh2(float a, float b) {
    h2 h; h.x = (_Float16)a; h.y = (_Float16)b;
    return __builtin_bit_cast(u32, h);
}

// non-temporal (evict-first) loads for the big per-step streams: these must
// NOT displace the 3.7MB weight set from the 4MB/XCD L2 (r3 lesson).
__device__ __forceinline__ float4 ntload_f4(const float* p) {
    f32x4 v = __builtin_nontemporal_load((const f32x4*)p);
    float4 r; r.x = v.x; r.y = v.y; r.z = v.z; r.w = v.w; return r;
}
__device__ __forceinline__ uint4 ntload_u4(const uint4* p) {
    u32x4 v = __builtin_nontemporal_load((const u32x4*)p);
    uint4 r; r.x = v.x; r.y = v.y; r.z = v.z; r.w = v.w; return r;
}
__device__ __forceinline__ float ntload_f(const float* p) {
    return __builtin_nontemporal_load(p);
}

// transpose: src (O x K) row-major -> dst (K x O)
__global__ void tkern(const float* __restrict__ src, float* __restrict__ dst, int O, int K) {
    int i = blockIdx.x * blockDim.x + threadIdx.x;
    if (i < O * K) {
        int o = i % O, k = i / O;
        dst[i] = src[o * K + k];
    }
}

// pack fp32 (O x K) -> f16 pairs: dst[(k/2)*O + o] = (w[o][2p], w[o][2p+1])
__global__ void packw(const float* __restrict__ src, u32* __restrict__ dst, int O, int K) {
    int i = blockIdx.x * blockDim.x + threadIdx.x;
    int n = O * (K >> 1);
    if (i < n) {
        int o = i % O, p = i / O;
        dst[i] = packh2(src[o * K + 2 * p], src[o * K + 2 * p + 1]);
    }
}

// pack inputs fp32 -> f16 pairs (same element order)
__global__ void packi(const float* __restrict__ src, u32* __restrict__ dst) {
    int i = blockIdx.x * blockDim.x + threadIdx.x;
    if (i < 8388608) dst[i] = packh2(src[2 * i], src[2 * i + 1]);
}

// mel staging [b][step][o=jj*80+mm] -> out [b][mm][7*step+jj]
__global__ void unmel(const float* __restrict__ ms, float* __restrict__ out) {
    int i = blockIdx.x * blockDim.x + threadIdx.x;
    if (i < 3584000) {
        int b = i / 56000, r = i % 56000;
        int mm = r / 700, c = r % 700;
        int step = c / 7, jj = c % 7;
        out[i] = ms[((size_t)b * 100 + step) * 560 + jj * 80 + mm];
    }
}

__global__ void prenet_kern(const float* __restrict__ memory,
                            const float* __restrict__ w1T, const float* __restrict__ b1,
                            const float* __restrict__ w2T, const float* __restrict__ b2,
                            float* __restrict__ p2all) {
    __shared__ float mi[80];
    __shared__ float p1[256];
    int blk = blockIdx.x;
    int t = blk >> 6, b = blk & 63;
    int tid = threadIdx.x;
    if (tid < 80) mi[tid] = (t == 0) ? 0.f : memory[(b * 700 + (7 * t - 1)) * 80 + tid];
    __syncthreads();
    float acc = b1[tid];
#pragma unroll 4
    for (int k = 0; k < 80; k++) acc += mi[k] * w1T[k * 256 + tid];
    p1[tid] = fmaxf(acc, 0.f);
    __syncthreads();
    if (tid < 128) {
        float a2 = b2[tid];
#pragma unroll 4
        for (int k = 0; k < 256; k++) a2 += p1[k] * w2T[k * 128 + tid];
        p2all[(t * 64 + b) * 128 + tid] = fmaxf(a2, 0.f);
    }
}

// proc_in -> f16, layout [b][t][a]
__global__ void proc_kern(const float* __restrict__ inputs, const float* __restrict__ inpT,
                          _Float16* __restrict__ procF) {
    __shared__ float xin[8][512];
    int blk = blockIdx.x;
    int b = blk >> 6, t0 = (blk & 63) << 3;
    int tid = threadIdx.x;
    for (int i = tid; i < 8 * 512; i += 1024)
        xin[i >> 9][i & 511] = inputs[((size_t)b * 512 + t0 + (i >> 9)) * 512 + (i & 511)];
    __syncthreads();
    int r = tid >> 7, a = tid & 127;
    float acc = 0.f;
#pragma unroll 4
    for (int d = 0; d < 512; d++) acc += xin[r][d] * inpT[d * 128 + a];
    procF[((size_t)(b * 512) + t0 + r) * 128 + a] = (_Float16)acc;
}

__launch_bounds__(1024, 1)
__global__ void decoder_kern(const float* __restrict__ inputs,
                             const u32* __restrict__ wsu,
                             const float* __restrict__ att_b_ih, const float* __restrict__ att_b_hh,
                             const float* __restrict__ v_w, const float* __restrict__ v_b,
                             const float* __restrict__ lcg, const float* __restrict__ lwg,
                             const float* __restrict__ pd_b,
                             const float* __restrict__ d1b_ih, const float* __restrict__ d1b_hh,
                             const float* __restrict__ d2b_ih, const float* __restrict__ d2b_hh,
                             const float* __restrict__ mel_b,
                             const float* __restrict__ stop_w, const float* __restrict__ stop_b,
                             float* __restrict__ out, int big) {
    const int b = blockIdx.x;
    const int tid = threadIdx.x;

    const uint4* w_attih = (const uint4*)(wsu + PK_ATTIH);
    const uint4* w_atthh = (const uint4*)(wsu + PK_ATTHH);
    const uint4* w_pd    = (const uint4*)(wsu + PK_PD);
    const uint4* w_d1ih  = (const uint4*)(wsu + PK_D1IH);
    const uint4* w_d1hh  = (const uint4*)(wsu + PK_D1HH);
    const uint4* w_d2ih  = (const uint4*)(wsu + PK_D2IH);
    const uint4* w_d2hh  = (const uint4*)(wsu + PK_D2HH);
    const uint4* w_mel   = (const uint4*)(wsu + PK_MEL);
    const _Float16* procF = (const _Float16*)(wsu + PROCF_U);
    const float* p2all   = (const float*)(wsu + P2ALL_U);
    const _Float16* inF16 = (const _Float16*)(wsu + INF16_U);
    float* mstage        = (float*)(wsu + MSTG_U);

    __shared__ float h_att[256], h1[256], h2[256], dec[256];
    __shared__ float awp[542], awcp[542];
    __shared__ __align__(16) float pqv[256];   // interleaved [pq[a], v_w[a]]
    __shared__ float ebuf[512], red[32], mout[560];
    __shared__ __align__(16) u32 cbuf[16 * 513]; // conv result f16 c-pairs [cp][t]; R7 f16-partial overlay
    __shared__ __align__(16) float scrA[4096];
    __shared__ __align__(16) float scrB[3072];
    __shared__ u32 xpatt[320];   // [p2 pairs 0..63 | ctx pairs 64..319]
    __shared__ u32 xppd[384];    // [h_att pairs 0..127 | ctx pairs 128..383]
    __shared__ u32 decp[128], h1p[128], h2p[128];
    __shared__ __align__(16) u32 lwp_lds[128 * 16];   // lwg as f16 c-pairs, [a][cp]
    __shared__ __align__(16) float lcgT[62 * 32];     // loc_conv transposed [ch*31+k][c]
    __shared__ float bias[5424]; // 0:att_ih 768:att_hh 1536:d1ih 2304:d1hh 3072:d2ih 3840:d2hh 4608:pd 4864:mel
    __shared__ float stopws[816];

    for (int i = tid; i < 256; i += 1024) { h_att[i] = 0.f; h1[i] = 0.f; h2[i] = 0.f; dec[i] = 0.f; }
    for (int i = tid; i < 542; i += 1024) { awp[i] = 0.f; awcp[i] = 0.f; }
    for (int i = tid; i < 320; i += 1024) xpatt[i] = 0u;
    for (int i = tid; i < 384; i += 1024) xppd[i] = 0u;
    if (tid < 128) { decp[tid] = 0u; h1p[tid] = 0u; h2p[tid] = 0u; }
    for (int i = tid; i < 2048; i += 1024)
        lwp_lds[i] = packh2(lwg[2 * i], lwg[2 * i + 1]);          // i = a*16+cp
    for (int i = tid; i < 62 * 32; i += 1024) {
        int k = i >> 5, c = i & 31;
        lcgT[i] = lcg[c * 62 + k];
    }
    if (tid < 768) {
        bias[tid] = att_b_ih[tid]; bias[768 + tid] = att_b_hh[tid];
        bias[1536 + tid] = d1b_ih[tid]; bias[2304 + tid] = d1b_hh[tid];
        bias[3072 + tid] = d2b_ih[tid]; bias[3840 + tid] = d2b_hh[tid];
    }
    if (tid < 256) bias[4608 + tid] = pd_b[tid];
    if (tid < 560) bias[4864 + tid] = mel_b[tid];
    if (tid < 816) stopws[tid] = stop_w[tid];
    if (tid < 128) { pqv[2 * tid] = 0.f; pqv[2 * tid + 1] = v_w[tid]; }
    if (tid >= 960) {   // pack p2 for step 0
        int j = tid - 960;
        xpatt[j] = packh2(p2all[(size_t)b * 128 + 2 * j], p2all[(size_t)b * 128 + 2 * j + 1]);
    }
    const float vb0 = v_b[0];
    const float sb0 = stop_b[0];
    __syncthreads();

    for (int step = 0; step < NSTEP; step++) {
        // ---- R1: att-GRU gate partials (768 thr: 192 og x 4 ks) ----
        if (tid < 768) {
            const int og = tid % 192;
            const int ks = tid / 192;
            float4 ai = {0.f, 0.f, 0.f, 0.f};
            float4 ah4 = {0.f, 0.f, 0.f, 0.f};
#pragma unroll 8
            for (int p = ks * 80; p < ks * 80 + 80; p++) {
                uint4 w = w_attih[p * 192 + og];
                u32 x = xpatt[p];
                ai.x = dot2(w.x, x, ai.x); ai.y = dot2(w.y, x, ai.y);
                ai.z = dot2(w.z, x, ai.z); ai.w = dot2(w.w, x, ai.w);
            }
#pragma unroll 8
            for (int p = ks * 32; p < ks * 32 + 32; p++) {
                uint4 w = w_atthh[p * 192 + og];
                u32 x = xppd[p];
                ah4.x = dot2(w.x, x, ah4.x); ah4.y = dot2(w.y, x, ah4.y);
                ah4.z = dot2(w.z, x, ah4.z); ah4.w = dot2(w.w, x, ah4.w);
            }
            *(float4*)&scrA[ks * 768 + og * 4] = ai;
            *(float4*)&scrB[ks * 768 + og * 4] = ah4;
        }
        __syncthreads();

        // ---- R2: att-GRU combine (128 thr x 2 outputs) + pack h_att pairs ----
        if (tid < 128) {
            float hv[2];
#pragma unroll
            for (int j = 0; j < 2; j++) {
                const int o = tid * 2 + j;
                float gr = bias[o], gz = bias[256 + o], gn = bias[512 + o];
                float hr = bias[768 + o], hz = bias[1024 + o], hn = bias[1280 + o];
#pragma unroll
                for (int s = 0; s < 4; s++) {
                    gr += scrA[s * 768 + o]; gz += scrA[s * 768 + 256 + o]; gn += scrA[s * 768 + 512 + o];
                    hr += scrB[s * 768 + o]; hz += scrB[s * 768 + 256 + o]; hn += scrB[s * 768 + 512 + o];
                }
                float r = sig_p(gr + hr), z = sig_p(gz + hz);
                float n = tanh_f(gn + r * hn);
                hv[j] = (1.f - z) * n + z * h_att[o];
                h_att[o] = hv[j];
            }
            xppd[tid] = packh2(hv[0], hv[1]);
        }
        __syncthreads();

        // ---- R3: q full-dot (128 thr -> pqv) || location conv (512 thr, LDS tables) ----
        if (tid < 128) {
            const u32* wqu = wsu + PK_Q;
            float qa = 0.f;
#pragma unroll 8
            for (int p = 0; p < 128; p++) qa = dot2(wqu[p * 128 + tid], xppd[p], qa);
            pqv[2 * tid] = qa;
        } else if (tid >= 512) {
            const int tp = tid - 512;
            float cr[32];
#pragma unroll
            for (int c = 0; c < 32; c++) cr[c] = 0.f;
#pragma clang loop unroll_count(2)
            for (int k = 0; k < 31; k++) {
                float a1 = awp[tp + k], a2 = awcp[tp + k];
                const float4* l1 = (const float4*)&lcgT[k * 32];
                const float4* l2 = (const float4*)&lcgT[(31 + k) * 32];
#pragma unroll
                for (int cc = 0; cc < 8; cc++) {
                    float4 w1 = l1[cc], w2 = l2[cc];
                    cr[4 * cc]     += w1.x * a1 + w2.x * a2;
                    cr[4 * cc + 1] += w1.y * a1 + w2.y * a2;
                    cr[4 * cc + 2] += w1.z * a1 + w2.z * a2;
                    cr[4 * cc + 3] += w1.w * a1 + w2.w * a2;
                }
            }
            // pre-pack for R5 (same pack point as before: numerics identical)
#pragma unroll
            for (int cp = 0; cp < 16; cp++) cbuf[cp * 513 + tp] = packh2(cr[2 * cp], cr[2 * cp + 1]);
        }
        __syncthreads();

        // ---- R5: attention energies. 16 waves = 4 t-groups x 4 a-groups,
        //          2 t per lane, lw from LDS broadcast, procF nt ----
        {
            const int wv = tid >> 6, lane = tid & 63;
            const int tg = wv & 3, ag = wv >> 2;
            const int a0 = ag << 5;
            const int t0 = (tg << 7) + lane;        // and t0+64
            u32 crA[16], crB[16];
#pragma unroll
            for (int cp = 0; cp < 16; cp++) {
                crA[cp] = cbuf[cp * 513 + t0];
                crB[cp] = cbuf[cp * 513 + t0 + 64];
            }
            const uint4* pfA = (const uint4*)(procF + ((size_t)(b * 512 + t0)) * 128 + a0);
            const uint4* pfB = (const uint4*)(procF + ((size_t)(b * 512 + t0 + 64)) * 128 + a0);
            float acc0 = 0.f, acc1 = 0.f;
#pragma unroll
            for (int l = 0; l < 4; l++) {
                U4 uA; uA.v = ntload_u4(pfA + l);
                U4 uB; uB.v = ntload_u4(pfB + l);
#pragma unroll
                for (int j = 0; j < 8; j++) {
                    const int a = a0 + l * 8 + j;
                    float2 pv = *(const float2*)&pqv[2 * a];
                    const uint4* lw = (const uint4*)&lwp_lds[a * 16];
                    uint4 w0 = lw[0], w1 = lw[1], w2 = lw[2], w3 = lw[3];
                    float s0 = pv.x + (float)uA.h[j];
                    float s1 = pv.x + (float)uB.h[j];
                    s0 = dot2(w0.x, crA[0], s0);  s1 = dot2(w0.x, crB[0], s1);
                    s0 = dot2(w0.y, crA[1], s0);  s1 = dot2(w0.y, crB[1], s1);
                    s0 = dot2(w0.z, crA[2], s0);  s1 = dot2(w0.z, crB[2], s1);
                    s0 = dot2(w0.w, crA[3], s0);  s1 = dot2(w0.w, crB[3], s1);
                    s0 = dot2(w1.x, crA[4], s0);  s1 = dot2(w1.x, crB[4], s1);
                    s0 = dot2(w1.y, crA[5], s0);  s1 = dot2(w1.y, crB[5], s1);
                    s0 = dot2(w1.z, crA[6], s0);  s1 = dot2(w1.z, crB[6], s1);
                    s0 = dot2(w1.w, crA[7], s0);  s1 = dot2(w1.w, crB[7], s1);
                    s0 = dot2(w2.x, crA[8], s0);  s1 = dot2(w2.x, crB[8], s1);
                    s0 = dot2(w2.y, crA[9], s0);  s1 = dot2(w2.y, crB[9], s1);
                    s0 = dot2(w2.z, crA[10], s0); s1 = dot2(w2.z, crB[10], s1);
                    s0 = dot2(w2.w, crA[11], s0); s1 = dot2(w2.w, crB[11], s1);
                    s0 = dot2(w3.x, crA[12], s0); s1 = dot2(w3.x, crB[12], s1);
                    s0 = dot2(w3.y, crA[13], s0); s1 = dot2(w3.y, crB[13], s1);
                    s0 = dot2(w3.z, crA[14], s0); s1 = dot2(w3.z, crB[14], s1);
                    s0 = dot2(w3.w, crA[15], s0); s1 = dot2(w3.w, crB[15], s1);
                    acc0 += pv.y * tanh_f(s0);
                    acc1 += pv.y * tanh_f(s1);
                }
            }
            scrB[ag * 512 + t0] = acc0;
            scrB[ag * 512 + t0 + 64] = acc1;
        }
        __syncthreads();

        // ---- R6: softmax over 512 + aw/awc + atts output (3 barriers) ----
        float e_reg = -1e30f;
        if (tid < 512)
            e_reg = scrB[tid] + scrB[512 + tid] + scrB[1024 + tid] + scrB[1536 + tid] + vb0;
        {
            float v = e_reg;
#pragma unroll
            for (int off = 32; off; off >>= 1) v = fmaxf(v, __shfl_down(v, off, 64));
            if (tid < 512 && (tid & 63) == 0) red[tid >> 6] = v;
        }
        __syncthreads();
        float smax = fmaxf(fmaxf(fmaxf(red[0], red[1]), fmaxf(red[2], red[3])),
                           fmaxf(fmaxf(red[4], red[5]), fmaxf(red[6], red[7])));
        float ex = 0.f;
        if (tid < 512) ex = __expf(e_reg - smax);
        {
            float v = ex;
#pragma unroll
            for (int off = 32; off; off >>= 1) v += __shfl_down(v, off, 64);
            if (tid < 512 && (tid & 63) == 0) red[8 + (tid >> 6)] = v;
        }
        __syncthreads();
        if (tid < 512) {
            float ssum = ((red[8] + red[9]) + (red[10] + red[11])) +
                         ((red[12] + red[13]) + (red[14] + red[15]));
            float al = ex * fastrcp(ssum);
            ebuf[tid] = al;
            awp[15 + tid] = al;
            awcp[15 + tid] += al;
            out[OUT_ATT + ((size_t)b * 100 + step) * 512 + tid] = al;
        }
        __syncthreads();

        // ---- R7: ctx partials. big: f16 inputs (16 ts x 64 dg, 8 d/thread);
        //          else: f32 round-1 path (8 ts x 128 dg) ----
        if (big) {
            const int dg = tid & 63, ts = tid >> 6;
            const uint4* ib = (const uint4*)(inF16 + ((size_t)b * 512 + ts * 32) * 512 + dg * 8);
            float4 p0 = {0.f, 0.f, 0.f, 0.f}, p1 = {0.f, 0.f, 0.f, 0.f};
#pragma unroll 8
            for (int t = 0; t < 32; t++) {
                float al = ebuf[ts * 32 + t];
                U4 u; u.v = ntload_u4(ib + (size_t)t * 64);
                p0.x += al * (float)u.h[0]; p0.y += al * (float)u.h[1];
                p0.z += al * (float)u.h[2]; p0.w += al * (float)u.h[3];
                p1.x += al * (float)u.h[4]; p1.y += al * (float)u.h[5];
                p1.z += al * (float)u.h[6]; p1.w += al * (float)u.h[7];
            }
            float* scrF = (float*)cbuf;   // overlay: cbuf free between R5 and next R3
            *(float4*)&scrF[ts * 512 + dg * 8] = p0;
            *(float4*)&scrF[ts * 512 + dg * 8 + 4] = p1;
        } else {
            const int dg = tid & 127, ts = tid >> 7;
            const float* ib = inputs + ((size_t)b * 512 + ts * 64) * 512;
            float4 acc = {0.f, 0.f, 0.f, 0.f};
#pragma unroll 8
            for (int t = 0; t < 64; t++) {
                float al = ebuf[ts * 64 + t];
                float4 xv = ntload_f4(ib + (size_t)t * 512 + dg * 4);
                acc.x += al * xv.x; acc.y += al * xv.y; acc.z += al * xv.z; acc.w += al * xv.w;
            }
            *(float4*)&scrA[ts * 512 + dg * 4] = acc;
        }
        __syncthreads();

        // ---- R8: ctx reduce + pack pairs ----
        if (tid < 256) {
            float s0 = 0.f, s1 = 0.f;
            if (big) {
                const float* scrF = (const float*)cbuf;
#pragma unroll
                for (int q = 0; q < 16; q++) { s0 += scrF[q * 512 + 2 * tid]; s1 += scrF[q * 512 + 2 * tid + 1]; }
            } else {
#pragma unroll
                for (int q = 0; q < 8; q++) { s0 += scrA[q * 512 + 2 * tid]; s1 += scrA[q * 512 + 2 * tid + 1]; }
            }
            u32 pr = packh2(s0, s1);
            xpatt[64 + tid] = pr;
            xppd[128 + tid] = pr;
        }
        __syncthreads();

        // ---- R9: pd partials (1024 thr: 64 og x 16 ks) ----
        {
            const int og = tid & 63, ks = tid >> 6;
            float4 acc = {0.f, 0.f, 0.f, 0.f};
#pragma unroll 8
            for (int p = ks * 24; p < ks * 24 + 24; p++) {
                uint4 w = w_pd[p * 64 + og];
                u32 x = xppd[p];
                acc.x = dot2(w.x, x, acc.x); acc.y = dot2(w.y, x, acc.y);
                acc.z = dot2(w.z, x, acc.z); acc.w = dot2(w.w, x, acc.w);
            }
            *(float4*)&scrA[ks * 256 + og * 4] = acc;
        }
        __syncthreads();

        // ---- R10: dec combine + pack ----
        if (tid < 128) {
            float d0 = bias[4608 + 2 * tid], d1 = bias[4608 + 2 * tid + 1];
#pragma unroll
            for (int q = 0; q < 16; q++) { d0 += scrA[q * 256 + 2 * tid]; d1 += scrA[q * 256 + 2 * tid + 1]; }
            dec[2 * tid] = d0; dec[2 * tid + 1] = d1;
            decp[tid] = packh2(d0, d1);
        }
        __syncthreads();

        // ---- R11: GRU1 partials ----
        if (tid < 768) {
            const int og = tid % 192;
            const int ks = tid / 192;
            float4 ai = {0.f, 0.f, 0.f, 0.f};
            float4 ah4 = {0.f, 0.f, 0.f, 0.f};
#pragma unroll 8
            for (int p = ks * 32; p < ks * 32 + 32; p++) {
                uint4 w1 = w_d1ih[p * 192 + og];
                uint4 w2 = w_d1hh[p * 192 + og];
                u32 xd = decp[p], xh = h1p[p];
                ai.x = dot2(w1.x, xd, ai.x); ai.y = dot2(w1.y, xd, ai.y);
                ai.z = dot2(w1.z, xd, ai.z); ai.w = dot2(w1.w, xd, ai.w);
                ah4.x = dot2(w2.x, xh, ah4.x); ah4.y = dot2(w2.y, xh, ah4.y);
                ah4.z = dot2(w2.z, xh, ah4.z); ah4.w = dot2(w2.w, xh, ah4.w);
            }
            *(float4*)&scrA[ks * 768 + og * 4] = ai;
            *(float4*)&scrB[ks * 768 + og * 4] = ah4;
        }
        __syncthreads();

        // ---- R12: GRU1 combine + residual + pack ----
        if (tid < 128) {
            float hv[2], dv[2];
#pragma unroll
            for (int j = 0; j < 2; j++) {
                const int o = tid * 2 + j;
                float gr = bias[1536 + o], gz = bias[1792 + o], gn = bias[2048 + o];
                float hr = bias[2304 + o], hz = bias[2560 + o], hn = bias[2816 + o];
#pragma unroll
                for (int s = 0; s < 4; s++) {
                    gr += scrA[s * 768 + o]; gz += scrA[s * 768 + 256 + o]; gn += scrA[s * 768 + 512 + o];
                    hr += scrB[s * 768 + o]; hz += scrB[s * 768 + 256 + o]; hn += scrB[s * 768 + 512 + o];
                }
                float r = sig_p(gr + hr), z = sig_p(gz + hz);
                float n = tanh_f(gn + r * hn);
                hv[j] = (1.f - z) * n + z * h1[o];
                h1[o] = hv[j];
                dv[j] = hv[j] + dec[o];
                dec[o] = dv[j];
            }
            h1p[tid] = packh2(hv[0], hv[1]);
            decp[tid] = packh2(dv[0], dv[1]);
        }
        __syncthreads();

        // ---- R13: GRU2 partials ----
        if (tid < 768) {
            const int og = tid % 192;
            const int ks = tid / 192;
            float4 ai = {0.f, 0.f, 0.f, 0.f};
            float4 ah4 = {0.f, 0.f, 0.f, 0.f};
#pragma unroll 8
            for (int p = ks * 32; p < ks * 32 + 32; p++) {
                uint4 w1 = w_d2ih[p * 192 + og];
                uint4 w2 = w_d2hh[p * 192 + og];
                u32 xd = decp[p], xh = h2p[p];
                ai.x = dot2(w1.x, xd, ai.x); ai.y = dot2(w1.y, xd, ai.y);
                ai.z = dot2(w1.z, xd, ai.z); ai.w = dot2(w1.w, xd, ai.w);
                ah4.x = dot2(w2.x, xh, ah4.x); ah4.y = dot2(w2.y, xh, ah4.y);
                ah4.z = dot2(w2.z, xh, ah4.z); ah4.w = dot2(w2.w, xh, ah4.w);
            }
            *(float4*)&scrA[ks * 768 + og * 4] = ai;
            *(float4*)&scrB[ks * 768 + og * 4] = ah4;
        }
        __syncthreads();

        // ---- R14: GRU2 combine + residual + pack ----
        if (tid < 128) {
            float hv[2], dv[2];
#pragma unroll
            for (int j = 0; j < 2; j++) {
                const int o = tid * 2 + j;
                float gr = bias[3072 + o], gz = bias[3328 + o], gn = bias[3584 + o];
                float hr = bias[3840 + o], hz = bias[4096 + o], hn = bias[4352 + o];
#pragma unroll
                for (int s = 0; s < 4; s++) {
                    gr += scrA[s * 768 + o]; gz += scrA[s * 768 + 256 + o]; gn += scrA[s * 768 + 512 + o];
                    hr += scrB[s * 768 + o]; hz += scrB[s * 768 + 256 + o]; hn += scrB[s * 768 + 512 + o];
                }
                float r = sig_p(gr + hr), z = sig_p(gz + hz);
                float n = tanh_f(gn + r * hn);
                hv[j] = (1.f - z) * n + z * h2[o];
                h2[o] = hv[j];
                dv[j] = hv[j] + dec[o];
                dec[o] = dv[j];
            }
            h2p[tid] = packh2(hv[0], hv[1]);
            decp[tid] = packh2(dv[0], dv[1]);
        }
        __syncthreads();

        // ---- R15: mel partials (560 thr: 140 og x 4 ks) ----
        if (tid < 560) {
            const int og = tid % 140;
            const int ks = tid / 140;
            float4 acc = {0.f, 0.f, 0.f, 0.f};
#pragma unroll 8
            for (int p = ks * 32; p < ks * 32 + 32; p++) {
                uint4 w = w_mel[p * 140 + og];
                u32 x = decp[p];
                acc.x = dot2(w.x, x, acc.x); acc.y = dot2(w.y, x, acc.y);
                acc.z = dot2(w.z, x, acc.z); acc.w = dot2(w.w, x, acc.w);
            }
            *(float4*)&scrA[ks * 560 + og * 4] = acc;
        }
        __syncthreads();

        // ---- R16: mel reduce + output (staged contiguously when big) ----
        if (tid < 280) {
#pragma unroll
            for (int j = 0; j < 2; j++) {
                const int o = 2 * tid + j;
                float m = bias[4864 + o];
#pragma unroll
                for (int s = 0; s < 4; s++) m += scrA[s * 560 + o];
                mout[o] = m;
                if (big) {
                    mstage[((size_t)b * 100 + step) * 560 + o] = m;
                } else {
                    int mm = o % 80, jj = o / 80;
                    out[((size_t)b * 80 + mm) * 700 + 7 * step + jj] = m;
                }
            }
        }
        __syncthreads();

        // ---- R17: stop token || prefetch+pack next p2 (no tail barrier) ----
        {
            float v = 0.f;
            if (tid < 816) v = ((tid < 256) ? dec[tid] : mout[tid - 256]) * stopws[tid];
            if (tid < 832) {
#pragma unroll
                for (int off = 32; off; off >>= 1) v += __shfl_down(v, off, 64);
                if ((tid & 63) == 0) red[tid >> 6] = v;
            }
            if (tid >= 960 && step + 1 < NSTEP) {
                int j = tid - 960;
                const float* p2n = p2all + ((size_t)(step + 1) * 64 + b) * 128;
                xpatt[j] = packh2(ntload_f(p2n + 2 * j), ntload_f(p2n + 2 * j + 1));
            }
        }
        __syncthreads();
        if (tid == 0) {
            float s = sb0;
            for (int w = 0; w < 13; w++) s += red[w];
            out[OUT_STOP + (size_t)b * 100 + step] = s;
        }
        // tail barrier dropped: next R1 touches only scrA/scrB (fenced above),
        // and red is next written in R6, several barriers after tid0's read.
    }
}

extern "C" void kernel_launch(void* const* d_in, const int* in_sizes, int n_in,
                              void* d_out, int out_size, void* d_ws, size_t ws_size,
                              hipStream_t stream) {
    const float* inputs    = (const float*)d_in[0];
    const float* memory    = (const float*)d_in[1];
    const float* prenet_w1 = (const float*)d_in[3];
    const float* prenet_b1 = (const float*)d_in[4];
    const float* prenet_w2 = (const float*)d_in[5];
    const float* prenet_b2 = (const float*)d_in[6];
    const float* att_w_ih  = (const float*)d_in[7];
    const float* att_w_hh  = (const float*)d_in[8];
    const float* att_b_ih  = (const float*)d_in[9];
    const float* att_b_hh  = (const float*)d_in[10];
    const float* q_w       = (const float*)d_in[11];
    const float* inp_w     = (const float*)d_in[12];
    const float* v_w       = (const float*)d_in[13];
    const float* v_b       = (const float*)d_in[14];
    const float* loc_conv  = (const float*)d_in[15];
    const float* loc_w     = (const float*)d_in[16];
    const float* pd_w      = (const float*)d_in[17];
    const float* pd_b      = (const float*)d_in[18];
    const float* d1_w_ih   = (const float*)d_in[19];
    const float* d1_w_hh   = (const float*)d_in[20];
    const float* d1_b_ih   = (const float*)d_in[21];
    const float* d1_b_hh   = (const float*)d_in[22];
    const float* d2_w_ih   = (const float*)d_in[23];
    const float* d2_w_hh   = (const float*)d_in[24];
    const float* d2_b_ih   = (const float*)d_in[25];
    const float* d2_b_hh   = (const float*)d_in[26];
    const float* mel_w     = (const float*)d_in[27];
    const float* mel_b     = (const float*)d_in[28];
    const float* stop_w    = (const float*)d_in[29];
    const float* stop_b    = (const float*)d_in[30];

    u32* wsu = (u32*)d_ws;
    float* out = (float*)d_out;
    const int big = ws_size >= (size_t)WS_NEED_U * 4u;

    auto P = [&](const float* src, int off, int O, int K) {
        int n = O * (K / 2);
        packw<<<(n + 255) / 256, 256, 0, stream>>>(src, wsu + off, O, K);
    };
    P(att_w_ih, PK_ATTIH, 768, 640);
    P(att_w_hh, PK_ATTHH, 768, 256);
    P(q_w,      PK_Q,     128, 256);
    P(pd_w,     PK_PD,    256, 768);
    P(d1_w_ih,  PK_D1IH,  768, 256);
    P(d1_w_hh,  PK_D1HH,  768, 256);
    P(d2_w_ih,  PK_D2IH,  768, 256);
    P(d2_w_hh,  PK_D2HH,  768, 256);
    P(mel_w,    PK_MEL,   560, 256);

    // prenet weight transposes (fp32)
    tkern<<<(256 * 80 + 255) / 256, 256, 0, stream>>>(prenet_w1, (float*)(wsu + W1T_U), 256, 80);
    tkern<<<(128 * 256 + 255) / 256, 256, 0, stream>>>(prenet_w2, (float*)(wsu + W2T_U), 128, 256);

    prenet_kern<<<6400, 256, 0, stream>>>(memory, (float*)(wsu + W1T_U), prenet_b1,
                                          (float*)(wsu + W2T_U), prenet_b2,
                                          (float*)(wsu + P2ALL_U));

    {
        float* inpT = (float*)(wsu + INPT_U);
        tkern<<<(128 * 512 + 255) / 256, 256, 0, stream>>>(inp_w, inpT, 128, 512);
        proc_kern<<<4096, 1024, 0, stream>>>(inputs, inpT, (_Float16*)(wsu + PROCF_U));
    }

    if (big) packi<<<32768, 256, 0, stream>>>(inputs, wsu + INF16_U);

    decoder_kern<<<64, 1024, 0, stream>>>(inputs, wsu,
                                          att_b_ih, att_b_hh, v_w, v_b,
                                          loc_conv, loc_w, pd_b,
                                          d1_b_ih, d1_b_hh, d2_b_ih, d2_b_hh,
                                          mel_b, stop_w, stop_b, out, big);

    if (big) unmel<<<14000, 256, 0, stream>>>((const float*)(wsu + MSTG_U), out);
}